// Round 16
// baseline (352.649 us; speedup 1.0000x reference)
//
#include <hip/hip_runtime.h>
#include <hip/hip_bf16.h>

using u16 = unsigned short;
typedef __bf16 bf16x8 __attribute__((ext_vector_type(8)));
typedef float f32x4 __attribute__((ext_vector_type(4)));

// B=4, S=512, KV=4096, D=1024, H=16, HD=64
#define SB 4
#define SS 512
#define SKV 4096
#define SD 1024
#define SH 16
#define SHD 64
#define NSPLIT 2
#define NROWS 32768   // B*H*S
#define QSCALE 0.18033688011112042f   // 0.125 * log2(e): softmax in base-2 domain
#define DEFER_THR 6.0f                // T13: P bounded by 2^6, skip rescale

__device__ inline u16 f2bf(float f){
  __hip_bfloat16 h = __float2bfloat16(f);
  return __builtin_bit_cast(u16, h);
}
__device__ inline float bf2f(u16 u){
  return __builtin_bit_cast(float, (unsigned)u << 16);
}

__device__ inline bf16x8 ld_frag_g(const u16* p){
  uint4 v = *reinterpret_cast<const uint4*>(p);
  return __builtin_bit_cast(bf16x8, v);
}

__device__ inline bf16x8 ld_frag_lds(const char* base, int ob){
  uint4 v = *reinterpret_cast<const uint4*>(base + ob);
  return __builtin_bit_cast(bf16x8, v);
}

// pack two positive f32 into 2 truncated bf16 (1 v_perm): {hi16(b), hi16(a)}
__device__ inline unsigned pack_bf_trunc(float a, float b){
  return __builtin_amdgcn_perm(__builtin_bit_cast(unsigned, b),
                               __builtin_bit_cast(unsigned, a), 0x07060302u);
}

// ---------- merged f32->bf16 casts: x (2048 blk) | xa (16384) | 4xW (4096) ----------
__global__ __launch_bounds__(256) void cast_all(const float* __restrict__ x,
                                                const float* __restrict__ xa,
                                                const float* __restrict__ Wq,
                                                const float* __restrict__ Wk,
                                                const float* __restrict__ Wv,
                                                const float* __restrict__ Wo,
                                                u16* __restrict__ xb,
                                                u16* __restrict__ xab,
                                                u16* __restrict__ Wqb){
  int bid = blockIdx.x;
  const float* s; u16* d; long j;
  if (bid < 2048){
    s = x;  d = xb;  j = (long)bid * 256 + threadIdx.x;
  } else if (bid < 18432){
    s = xa; d = xab; j = (long)(bid - 2048) * 256 + threadIdx.x;
  } else {
    int wb = bid - 18432;
    int which = wb >> 10;
    s = which == 0 ? Wq : which == 1 ? Wk : which == 2 ? Wv : Wo;
    d = Wqb + (long)which * 1048576L;
    j = (long)(wb & 1023) * 256 + threadIdx.x;
  }
  float4 f = reinterpret_cast<const float4*>(s)[j];
  ushort4 u;
  u.x = f2bf(f.x); u.y = f2bf(f.y); u.z = f2bf(f.z); u.w = f2bf(f.w);
  reinterpret_cast<ushort4*>(d)[j] = u;
}

enum { MODE_Q = 0, MODE_K = 1, MODE_V = 2, MODE_OUT = 3 };

// ---------- merged Q+K+V projection, R12-verified 128^2 dbuf body ----------
// blocks [0,128): Q; [128,1152): K; [1152,2176): V (XCD-chunked remap).
__global__ __launch_bounds__(256) void proj_all(const u16* __restrict__ xb,
                                                const u16* __restrict__ xab,
                                                const u16* __restrict__ Wqb,
                                                const u16* __restrict__ Wkb,
                                                const u16* __restrict__ Wvb,
                                                const float* __restrict__ bq,
                                                const float* __restrict__ bv,
                                                u16* __restrict__ qbuf,
                                                float* __restrict__ outK,
                                                u16* __restrict__ kbuf,
                                                float* __restrict__ outV,
                                                u16* __restrict__ vTbuf)
{
  __shared__ u16 As[2][128*64];
  __shared__ u16 Bs[2][128*64];
  const int tid  = threadIdx.x;
  const int lane = tid & 63;
  const int wm   = ((tid >> 6) >> 1) * 64;
  const int wn   = ((tid >> 6) & 1) * 64;

  int mode;
  const u16 *A, *W;
  long rowBase, colBase;
  {
    int bid = blockIdx.x;
    if (bid < 128){
      mode = MODE_Q; A = xb; W = Wqb;
      rowBase = (long)(bid >> 3) * 128;
      colBase = (long)(bid & 7) * 128;
    } else {
      int lin = bid - 128;
      if (lin < 1024){ mode = MODE_K; W = Wkb; }
      else           { mode = MODE_V; W = Wvb; lin -= 1024; }
      A = xab;
      int xcd = lin & 7, j = lin >> 3;      // XCD-chunked (R9-verified)
      rowBase = (long)(xcd * 16 + (j >> 3)) * 128;
      colBase = (long)(j & 7) * 128;
    }
  }

  f32x4 acc[4][4];
#pragma unroll
  for (int i = 0; i < 4; i++)
#pragma unroll
    for (int j = 0; j < 4; j++)
      acc[i][j] = (f32x4){0.f, 0.f, 0.f, 0.f};

  uint4 va[4], vw[4];
#pragma unroll
  for (int i = 0; i < 4; i++){
    int u = tid + i * 256;
    int r = u >> 3, c = u & 7;
    va[i] = *reinterpret_cast<const uint4*>(A + (rowBase + r) * 1024 + c * 8);
    vw[i] = *reinterpret_cast<const uint4*>(W + (colBase + r) * 1024 + c * 8);
  }
#pragma unroll
  for (int i = 0; i < 4; i++){
    int u = tid + i * 256;
    int r = u >> 3, c = u & 7;
    int ob = (r * 128 + c * 16) ^ ((r & 7) << 4);
    *reinterpret_cast<uint4*>(reinterpret_cast<char*>(As[0]) + ob) = va[i];
    *reinterpret_cast<uint4*>(reinterpret_cast<char*>(Bs[0]) + ob) = vw[i];
  }
  __syncthreads();

  int cur = 0;
  for (int kt = 0; kt < 16; ++kt){
    uint4 va2[4], vw2[4];
    if (kt < 15){
#pragma unroll
      for (int i = 0; i < 4; i++){
        int u = tid + i * 256;
        int r = u >> 3, c = u & 7;
        va2[i] = *reinterpret_cast<const uint4*>(A + (rowBase + r) * 1024 + (kt + 1) * 64 + c * 8);
        vw2[i] = *reinterpret_cast<const uint4*>(W + (colBase + r) * 1024 + (kt + 1) * 64 + c * 8);
      }
    }
    const char* ach = reinterpret_cast<const char*>(As[cur]);
    const char* bch = reinterpret_cast<const char*>(Bs[cur]);
    __builtin_amdgcn_s_setprio(1);
#pragma unroll
    for (int kk = 0; kk < 2; kk++){
      bf16x8 af[4], bfr[4];
#pragma unroll
      for (int mi = 0; mi < 4; mi++){
        int row = wm + mi * 16 + (lane & 15);
        int ob = (row * 128 + kk * 64 + (lane >> 4) * 16) ^ ((row & 7) << 4);
        af[mi] = ld_frag_lds(ach, ob);
      }
#pragma unroll
      for (int ni = 0; ni < 4; ni++){
        int row = wn + ni * 16 + (lane & 15);
        int ob = (row * 128 + kk * 64 + (lane >> 4) * 16) ^ ((row & 7) << 4);
        bfr[ni] = ld_frag_lds(bch, ob);
      }
#pragma unroll
      for (int mi = 0; mi < 4; mi++)
#pragma unroll
        for (int ni = 0; ni < 4; ni++)
          acc[mi][ni] = __builtin_amdgcn_mfma_f32_16x16x32_bf16(af[mi], bfr[ni], acc[mi][ni], 0, 0, 0);
    }
    __builtin_amdgcn_s_setprio(0);
    if (kt < 15){
#pragma unroll
      for (int i = 0; i < 4; i++){
        int u = tid + i * 256;
        int r = u >> 3, c = u & 7;
        int ob = (r * 128 + c * 16) ^ ((r & 7) << 4);
        *reinterpret_cast<uint4*>(reinterpret_cast<char*>(As[cur ^ 1]) + ob) = va2[i];
        *reinterpret_cast<uint4*>(reinterpret_cast<char*>(Bs[cur ^ 1]) + ob) = vw2[i];
      }
      __syncthreads();
    }
    cur ^= 1;
  }

#pragma unroll
  for (int mi = 0; mi < 4; mi++){
#pragma unroll
    for (int ni = 0; ni < 4; ni++){
      long gn = colBase + wn + ni * 16 + (lane & 15);
      long h = gn >> 6, hd = gn & 63;
      if (mode == MODE_Q){
        float bb = bq[gn];
#pragma unroll
        for (int r = 0; r < 4; r++){
          long gm = rowBase + wm + mi * 16 + ((lane >> 4) << 2) + r;
          long b = gm >> 9, s = gm & 511;
          qbuf[((b * SH + h) * SS + s) * SHD + hd] =
              f2bf((acc[mi][ni][r] + bb) * QSCALE);
        }
      } else if (mode == MODE_K){
#pragma unroll
        for (int r = 0; r < 4; r++){
          long gm = rowBase + wm + mi * 16 + ((lane >> 4) << 2) + r;
          long b = gm >> 12, kv = gm & 4095;
          long idx = ((b * SH + h) * SKV + kv) * SHD + hd;
          float val = acc[mi][ni][r];
          outK[idx] = val;
          kbuf[idx] = f2bf(val);
        }
      } else { // MODE_V
        float bb = bv[gn];
        long gmBase = rowBase + wm + mi * 16 + ((lane >> 4) << 2);
        long b = gmBase >> 12, kv = gmBase & 4095;
        long fidx = ((b * SH + h) * SKV + kv) * SHD + hd;
        ushort4 pk;
        float v0 = acc[mi][ni][0] + bb; outV[fidx          ] = v0; pk.x = f2bf(v0);
        float v1 = acc[mi][ni][1] + bb; outV[fidx +     SHD] = v1; pk.y = f2bf(v1);
        float v2 = acc[mi][ni][2] + bb; outV[fidx + 2 * SHD] = v2; pk.z = f2bf(v2);
        float v3 = acc[mi][ni][3] + bb; outV[fidx + 3 * SHD] = v3; pk.w = f2bf(v3);
        *reinterpret_cast<ushort4*>(vTbuf + ((b * SH + h) * SHD + hd) * SKV + kv) = pk;
      }
    }
  }
}

// ---------- OUT projection: R12-verified 128^2 dbuf ----------
__global__ __launch_bounds__(256) void gemm_out(const u16* __restrict__ A,
                                                const u16* __restrict__ W,
                                                const float* __restrict__ bias,
                                                float* __restrict__ outF)
{
  __shared__ u16 As[2][128*64];
  __shared__ u16 Bs[2][128*64];
  const int tid  = threadIdx.x;
  const int lane = tid & 63;
  const int wm   = ((tid >> 6) >> 1) * 64;
  const int wn   = ((tid >> 6) & 1) * 64;
  const long rowBase = (long)blockIdx.x * 128;
  const long colBase = (long)blockIdx.y * 128;

  f32x4 acc[4][4];
#pragma unroll
  for (int i = 0; i < 4; i++)
#pragma unroll
    for (int j = 0; j < 4; j++)
      acc[i][j] = (f32x4){0.f, 0.f, 0.f, 0.f};

  uint4 va[4], vw[4];
#pragma unroll
  for (int i = 0; i < 4; i++){
    int u = tid + i * 256;
    int r = u >> 3, c = u & 7;
    va[i] = *reinterpret_cast<const uint4*>(A + (rowBase + r) * 1024 + c * 8);
    vw[i] = *reinterpret_cast<const uint4*>(W + (colBase + r) * 1024 + c * 8);
  }
#pragma unroll
  for (int i = 0; i < 4; i++){
    int u = tid + i * 256;
    int r = u >> 3, c = u & 7;
    int ob = (r * 128 + c * 16) ^ ((r & 7) << 4);
    *reinterpret_cast<uint4*>(reinterpret_cast<char*>(As[0]) + ob) = va[i];
    *reinterpret_cast<uint4*>(reinterpret_cast<char*>(Bs[0]) + ob) = vw[i];
  }
  __syncthreads();

  int cur = 0;
  for (int kt = 0; kt < 16; ++kt){
    uint4 va2[4], vw2[4];
    if (kt < 15){
#pragma unroll
      for (int i = 0; i < 4; i++){
        int u = tid + i * 256;
        int r = u >> 3, c = u & 7;
        va2[i] = *reinterpret_cast<const uint4*>(A + (rowBase + r) * 1024 + (kt + 1) * 64 + c * 8);
        vw2[i] = *reinterpret_cast<const uint4*>(W + (colBase + r) * 1024 + (kt + 1) * 64 + c * 8);
      }
    }
    const char* ach = reinterpret_cast<const char*>(As[cur]);
    const char* bch = reinterpret_cast<const char*>(Bs[cur]);
    __builtin_amdgcn_s_setprio(1);
#pragma unroll
    for (int kk = 0; kk < 2; kk++){
      bf16x8 af[4], bfr[4];
#pragma unroll
      for (int mi = 0; mi < 4; mi++){
        int row = wm + mi * 16 + (lane & 15);
        int ob = (row * 128 + kk * 64 + (lane >> 4) * 16) ^ ((row & 7) << 4);
        af[mi] = ld_frag_lds(ach, ob);
      }
#pragma unroll
      for (int ni = 0; ni < 4; ni++){
        int row = wn + ni * 16 + (lane & 15);
        int ob = (row * 128 + kk * 64 + (lane >> 4) * 16) ^ ((row & 7) << 4);
        bfr[ni] = ld_frag_lds(bch, ob);
      }
#pragma unroll
      for (int mi = 0; mi < 4; mi++)
#pragma unroll
        for (int ni = 0; ni < 4; ni++)
          acc[mi][ni] = __builtin_amdgcn_mfma_f32_16x16x32_bf16(af[mi], bfr[ni], acc[mi][ni], 0, 0, 0);
    }
    __builtin_amdgcn_s_setprio(0);
    if (kt < 15){
#pragma unroll
      for (int i = 0; i < 4; i++){
        int u = tid + i * 256;
        int r = u >> 3, c = u & 7;
        int ob = (r * 128 + c * 16) ^ ((r & 7) << 4);
        *reinterpret_cast<uint4*>(reinterpret_cast<char*>(As[cur ^ 1]) + ob) = va2[i];
        *reinterpret_cast<uint4*>(reinterpret_cast<char*>(Bs[cur ^ 1]) + ob) = vw2[i];
      }
      __syncthreads();
    }
    cur ^= 1;
  }

#pragma unroll
  for (int mi = 0; mi < 4; mi++){
#pragma unroll
    for (int ni = 0; ni < 4; ni++){
      long gn = colBase + wn + ni * 16 + (lane & 15);
      float bb = bias[gn];
#pragma unroll
      for (int r = 0; r < 4; r++){
        long gm = rowBase + wm + mi * 16 + ((lane >> 4) << 2) + r;
        outF[gm * 1024 + gn] = acc[mi][ni][r] + bb;
      }
    }
  }
}

// ---------- flash attention partial: NSPLIT=2 (32 iters/block) + setprio ----------
__global__ __launch_bounds__(512) void attn_partial(const u16* __restrict__ qb,
                                                    const u16* __restrict__ kb,
                                                    const u16* __restrict__ vTb,
                                                    u16* __restrict__ opartB,
                                                    float* __restrict__ ml){
  __shared__ u16 Klds[2][64 * 64];
  __shared__ u16 Vlds[2][64 * 64];
  __shared__ u16 PT[8][16 * 72];
  const int tid  = threadIdx.x;
  const int lane = tid & 63;
  const int wid  = tid >> 6;
  const int c    = lane & 15;
  const int hi   = lane >> 4;
  const long bh  = blockIdx.x;
  const int  qt  = blockIdx.y;
  const int  split = blockIdx.z;

  const u16* qp = qb + (bh * SS + qt * 128 + wid * 16 + c) * SHD + hi * 8;
  const bf16x8 bq0 = ld_frag_g(qp);
  const bf16x8 bq1 = ld_frag_g(qp + 32);

  f32x4 acc[4];
#pragma unroll
  for (int i = 0; i < 4; i++) acc[i] = (f32x4){0.f, 0.f, 0.f, 0.f};
  float mrun = -INFINITY;
  f32x4 lrunv = (f32x4){0.f, 0.f, 0.f, 0.f};

  const u16* kbase = kb  + bh * SKV * SHD;
  const u16* vbase = vTb + bh * SHD * SKV;
  u16* pt = &PT[wid][0];
  const int sr  = tid >> 3;
  const int scc = tid & 7;
  const int sob = (sr * 128 + scc * 16) ^ ((sr & 7) << 4);
  const int t0 = split * 32;                // NSPLIT=2: 32 KV-64 tiles each

  {
    uint4 kv4 = *reinterpret_cast<const uint4*>(kbase + (t0 * 64 + sr) * SHD + scc * 8);
    uint4 vv4 = *reinterpret_cast<const uint4*>(vbase + (long)sr * SKV + t0 * 64 + scc * 8);
    *reinterpret_cast<uint4*>(reinterpret_cast<char*>(Klds[0]) + sob) = kv4;
    *reinterpret_cast<uint4*>(reinterpret_cast<char*>(Vlds[0]) + sob) = vv4;
  }
  __syncthreads();

  int cur = 0;
  for (int kt = t0; kt < t0 + 32; ++kt){
    const bool hn = kt + 1 < t0 + 32;
    uint4 kn, vn;
    if (hn){
      kn = *reinterpret_cast<const uint4*>(kbase + ((kt + 1) * 64 + sr) * SHD + scc * 8);
      vn = *reinterpret_cast<const uint4*>(vbase + (long)sr * SKV + (kt + 1) * 64 + scc * 8);
    }
    const char* kch = reinterpret_cast<const char*>(Klds[cur]);
    const char* vch = reinterpret_cast<const char*>(Vlds[cur]);

    f32x4 sT[4];
    __builtin_amdgcn_s_setprio(1);
#pragma unroll
    for (int ni = 0; ni < 4; ni++){
      int krow = ni * 16 + c;
      int swz = (krow & 7) << 4;
      int a0 = (krow * 128 + hi * 16) ^ swz;
      int a1 = (krow * 128 + 64 + hi * 16) ^ swz;
      f32x4 z = (f32x4){0.f, 0.f, 0.f, 0.f};
      sT[ni] = __builtin_amdgcn_mfma_f32_16x16x32_bf16(ld_frag_lds(kch, a0), bq0, z, 0, 0, 0);
      sT[ni] = __builtin_amdgcn_mfma_f32_16x16x32_bf16(ld_frag_lds(kch, a1), bq1, sT[ni], 0, 0, 0);
    }
    __builtin_amdgcn_s_setprio(0);
    f32x4 mv = __builtin_elementwise_max(__builtin_elementwise_max(sT[0], sT[1]),
                                         __builtin_elementwise_max(sT[2], sT[3]));
    float t = fmaxf(fmaxf(mv[0], mv[1]), fmaxf(mv[2], mv[3]));
    if (!__all(t <= mrun + DEFER_THR)){
      float tr = fmaxf(t, __shfl_xor(t, 16));
      tr = fmaxf(tr, __shfl_xor(tr, 32));
      float mn = fmaxf(mrun, tr);
      float al = exp2f(mrun - mn);
      lrunv *= al;
#pragma unroll
      for (int ni = 0; ni < 4; ni++) acc[ni] *= al;
      mrun = mn;
    }
#pragma unroll
    for (int ni = 0; ni < 4; ni++){
      f32x4 p;
      p[0] = exp2f(sT[ni][0] - mrun); p[1] = exp2f(sT[ni][1] - mrun);
      p[2] = exp2f(sT[ni][2] - mrun); p[3] = exp2f(sT[ni][3] - mrun);
      lrunv += p;
      unsigned lo = pack_bf_trunc(p[0], p[1]);
      unsigned hp = pack_bf_trunc(p[2], p[3]);
      uint2 w; w.x = lo; w.y = hp;
      *reinterpret_cast<uint2*>(pt + c * 72 + ni * 16 + hi * 4) = w;
    }
    __builtin_amdgcn_s_setprio(1);
#pragma unroll
    for (int m = 0; m < 2; m++){
      bf16x8 pfrag = __builtin_bit_cast(bf16x8,
          *reinterpret_cast<const uint4*>(pt + c * 72 + m * 32 + hi * 8));
#pragma unroll
      for (int ni = 0; ni < 4; ni++){
        int vrow = ni * 16 + c;
        int av = (vrow * 128 + m * 64 + hi * 16) ^ ((vrow & 7) << 4);
        acc[ni] = __builtin_amdgcn_mfma_f32_16x16x32_bf16(ld_frag_lds(vch, av), pfrag, acc[ni], 0, 0, 0);
      }
    }
    __builtin_amdgcn_s_setprio(0);
    if (hn){
      *reinterpret_cast<uint4*>(reinterpret_cast<char*>(Klds[cur ^ 1]) + sob) = kn;
      *reinterpret_cast<uint4*>(reinterpret_cast<char*>(Vlds[cur ^ 1]) + sob) = vn;
      __syncthreads();
    }
    cur ^= 1;
  }

  float l = (lrunv[0] + lrunv[1]) + (lrunv[2] + lrunv[3]);
  l += __shfl_xor(l, 16);
  l += __shfl_xor(l, 32);
  const long row = bh * SS + (long)qt * 128 + wid * 16 + c;
  u16* ob = opartB + ((long)split * NROWS + row) * SHD;
#pragma unroll
  for (int ni = 0; ni < 4; ni++){
    ushort4 pk;
    pk.x = f2bf(acc[ni][0]); pk.y = f2bf(acc[ni][1]);
    pk.z = f2bf(acc[ni][2]); pk.w = f2bf(acc[ni][3]);
    *reinterpret_cast<ushort4*>(ob + ni * 16 + hi * 4) = pk;
  }
  if (hi == 0){
    ml[(long)split * NROWS + row] = mrun;
    ml[(long)NSPLIT * NROWS + (long)split * NROWS + row] = l;
  }
}

// ---------- combine bf16 partials (2 splits) -> attnb bf16 [B,S,D] ----------
__global__ __launch_bounds__(256) void attn_combine(const u16* __restrict__ opartB,
                                                    const float* __restrict__ ml,
                                                    u16* __restrict__ attnb){
  long idx4 = (long)blockIdx.x * 256 + threadIdx.x;
  long row = idx4 >> 4;
  int  c   = (int)(idx4 & 15);
  float m0 = ml[row], m1 = ml[NROWS + row];
  float M = fmaxf(m0, m1);
  float w0 = exp2f(m0 - M), w1 = exp2f(m1 - M);
  const float* lb = ml + (long)NSPLIT * NROWS;
  float L = w0 * lb[row] + w1 * lb[NROWS + row];
  float inv = 1.f / L;
  const ushort4* op = reinterpret_cast<const ushort4*>(opartB);
  ushort4 v0 = op[(0L*NROWS + row) * 16 + c];
  ushort4 v1 = op[(1L*NROWS + row) * 16 + c];
  float4 val;
  val.x = (w0*bf2f(v0.x) + w1*bf2f(v1.x)) * inv;
  val.y = (w0*bf2f(v0.y) + w1*bf2f(v1.y)) * inv;
  val.z = (w0*bf2f(v0.z) + w1*bf2f(v1.z)) * inv;
  val.w = (w0*bf2f(v0.w) + w1*bf2f(v1.w)) * inv;
  long bh = row >> 9, s = row & 511;
  long b = bh >> 4, h = bh & 15;
  ushort4 u;
  u.x = f2bf(val.x); u.y = f2bf(val.y); u.z = f2bf(val.z); u.w = f2bf(val.w);
  reinterpret_cast<ushort4*>(attnb)[((b * SS + s) * SD + h * SHD) / 4 + c] = u;
}

extern "C" void kernel_launch(void* const* d_in, const int* in_sizes, int n_in,
                              void* d_out, int out_size, void* d_ws, size_t ws_size,
                              hipStream_t stream)
{
  const float* x  = (const float*)d_in[0];
  const float* xa = (const float*)d_in[1];
  const float* Wq = (const float*)d_in[2];
  const float* bq = (const float*)d_in[3];
  const float* Wk = (const float*)d_in[4];
  const float* Wv = (const float*)d_in[5];
  const float* bv = (const float*)d_in[6];
  const float* Wo = (const float*)d_in[7];
  const float* bo = (const float*)d_in[8];

  float* outO = (float*)d_out;
  float* outK = outO + (long)SB * SS * SD;
  float* outV = outK + (long)SB * SH * SKV * SHD;

  u16* ws   = (u16*)d_ws;
  u16* xb   = ws;                                     // 2M u16 (reused as attnb)
  u16* xab  = xb   + 2097152L;                        // 16.7M u16 (reused as opartB)
  u16* Wqb  = xab  + 16777216L;                       // 4x 1M u16 (Wq,Wk,Wv,Wo)
  u16* Wkb  = Wqb  + 1048576L;
  u16* Wvb  = Wkb  + 1048576L;
  u16* Wob  = Wvb  + 1048576L;
  u16* qbuf = Wob  + 1048576L;                        // [B,H,S,HD] bf16
  u16* kbuf = qbuf + 2097152L;                        // [B,H,KV,HD] bf16
  u16* vTbuf= kbuf + 16777216L;                       // [B,H,HD,KV] bf16
  u16* mlb  = vTbuf+ 16777216L;                       // 4*32768 f32

  u16*   attnb  = xb;                                 // alias: xb dead after proj_all
  u16*   opartB = xab;                                // alias: xab dead after proj_all
  float* ml     = (float*)mlb;

  cast_all<<<22528, 256, 0, stream>>>(x, xa, Wq, Wk, Wv, Wo, xb, xab, Wqb);

  proj_all<<<2176, 256, 0, stream>>>(xb, xab, Wqb, Wkb, Wvb, bq, bv,
                                     qbuf, outK, kbuf, outV, vTbuf);
  attn_partial<<<dim3(64, 4, NSPLIT), 512, 0, stream>>>(qbuf, kbuf, vTbuf, opartB, ml);
  attn_combine<<<2048, 256, 0, stream>>>(opartB, ml, attnb);
  gemm_out    <<<dim3(16, 8), 256, 0, stream>>>(attnb, Wob, bo, outO);
}

// Round 17
// 242.972 us; speedup vs baseline: 1.4514x; 1.4514x over previous
//
#include <hip/hip_runtime.h>
#include <hip/hip_bf16.h>

using u16 = unsigned short;
typedef __bf16 bf16x8 __attribute__((ext_vector_type(8)));
typedef float f32x4 __attribute__((ext_vector_type(4)));

// B=4, S=512, KV=4096, D=1024, H=16, HD=64
#define SB 4
#define SS 512
#define SKV 4096
#define SD 1024
#define SH 16
#define SHD 64
#define NSPLIT 4
#define NROWS 32768   // B*H*S
#define QSCALE 0.18033688011112042f   // 0.125 * log2(e): softmax in base-2 domain
#define DEFER_THR 6.0f                // T13: P bounded by 2^6, skip rescale

__device__ inline u16 f2bf(float f){
  __hip_bfloat16 h = __float2bfloat16(f);
  return __builtin_bit_cast(u16, h);
}
__device__ inline float bf2f(u16 u){
  return __builtin_bit_cast(float, (unsigned)u << 16);
}

__device__ inline bf16x8 ld_frag_g(const u16* p){
  uint4 v = *reinterpret_cast<const uint4*>(p);
  return __builtin_bit_cast(bf16x8, v);
}

__device__ inline bf16x8 ld_frag_lds(const char* base, int ob){
  uint4 v = *reinterpret_cast<const uint4*>(base + ob);
  return __builtin_bit_cast(bf16x8, v);
}

// pack two positive f32 into 2 truncated bf16 (1 v_perm): {hi16(b), hi16(a)}
__device__ inline unsigned pack_bf_trunc(float a, float b){
  return __builtin_amdgcn_perm(__builtin_bit_cast(unsigned, b),
                               __builtin_bit_cast(unsigned, a), 0x07060302u);
}

// ---------- merged f32->bf16 casts: x (2048 blk) | xa (16384) | 4xW (4096) ----------
__global__ __launch_bounds__(256) void cast_all(const float* __restrict__ x,
                                                const float* __restrict__ xa,
                                                const float* __restrict__ Wq,
                                                const float* __restrict__ Wk,
                                                const float* __restrict__ Wv,
                                                const float* __restrict__ Wo,
                                                u16* __restrict__ xb,
                                                u16* __restrict__ xab,
                                                u16* __restrict__ Wqb){
  int bid = blockIdx.x;
  const float* s; u16* d; long j;
  if (bid < 2048){
    s = x;  d = xb;  j = (long)bid * 256 + threadIdx.x;
  } else if (bid < 18432){
    s = xa; d = xab; j = (long)(bid - 2048) * 256 + threadIdx.x;
  } else {
    int wb = bid - 18432;
    int which = wb >> 10;
    s = which == 0 ? Wq : which == 1 ? Wk : which == 2 ? Wv : Wo;
    d = Wqb + (long)which * 1048576L;
    j = (long)(wb & 1023) * 256 + threadIdx.x;
  }
  float4 f = reinterpret_cast<const float4*>(s)[j];
  ushort4 u;
  u.x = f2bf(f.x); u.y = f2bf(f.y); u.z = f2bf(f.z); u.w = f2bf(f.w);
  reinterpret_cast<ushort4*>(d)[j] = u;
}

enum { MODE_Q = 0, MODE_K = 1, MODE_V = 2, MODE_OUT = 3 };

// ---------- merged Q+K+V projection, R12-verified 128^2 dbuf body ----------
// blocks [0,128): Q (16x8 tiles of x@Wq^T); [128,1152): K; [1152,2176): V.
// K/V use the XCD-chunked remap (offset 128/1152 both = 0 mod 8, mapping kept).
__global__ __launch_bounds__(256) void proj_all(const u16* __restrict__ xb,
                                                const u16* __restrict__ xab,
                                                const u16* __restrict__ Wqb,
                                                const u16* __restrict__ Wkb,
                                                const u16* __restrict__ Wvb,
                                                const float* __restrict__ bq,
                                                const float* __restrict__ bv,
                                                u16* __restrict__ qbuf,
                                                float* __restrict__ outK,
                                                u16* __restrict__ kbuf,
                                                float* __restrict__ outV,
                                                u16* __restrict__ vTbuf)
{
  __shared__ u16 As[2][128*64];
  __shared__ u16 Bs[2][128*64];
  const int tid  = threadIdx.x;
  const int lane = tid & 63;
  const int wm   = ((tid >> 6) >> 1) * 64;
  const int wn   = ((tid >> 6) & 1) * 64;

  int mode;
  const u16 *A, *W;
  long rowBase, colBase;
  {
    int bid = blockIdx.x;
    if (bid < 128){
      mode = MODE_Q; A = xb; W = Wqb;
      rowBase = (long)(bid >> 3) * 128;     // 16 row tiles (M=2048)
      colBase = (long)(bid & 7) * 128;
    } else {
      int lin = bid - 128;
      if (lin < 1024){ mode = MODE_K; W = Wkb; }
      else           { mode = MODE_V; W = Wvb; lin -= 1024; }
      A = xab;
      int xcd = lin & 7, j = lin >> 3;      // XCD-chunked (R9-verified)
      rowBase = (long)(xcd * 16 + (j >> 3)) * 128;
      colBase = (long)(j & 7) * 128;
    }
  }

  f32x4 acc[4][4];
#pragma unroll
  for (int i = 0; i < 4; i++)
#pragma unroll
    for (int j = 0; j < 4; j++)
      acc[i][j] = (f32x4){0.f, 0.f, 0.f, 0.f};

  uint4 va[4], vw[4];
#pragma unroll
  for (int i = 0; i < 4; i++){
    int u = tid + i * 256;
    int r = u >> 3, c = u & 7;
    va[i] = *reinterpret_cast<const uint4*>(A + (rowBase + r) * 1024 + c * 8);
    vw[i] = *reinterpret_cast<const uint4*>(W + (colBase + r) * 1024 + c * 8);
  }
#pragma unroll
  for (int i = 0; i < 4; i++){
    int u = tid + i * 256;
    int r = u >> 3, c = u & 7;
    int ob = (r * 128 + c * 16) ^ ((r & 7) << 4);
    *reinterpret_cast<uint4*>(reinterpret_cast<char*>(As[0]) + ob) = va[i];
    *reinterpret_cast<uint4*>(reinterpret_cast<char*>(Bs[0]) + ob) = vw[i];
  }
  __syncthreads();

  int cur = 0;
  for (int kt = 0; kt < 16; ++kt){
    uint4 va2[4], vw2[4];
    if (kt < 15){
#pragma unroll
      for (int i = 0; i < 4; i++){
        int u = tid + i * 256;
        int r = u >> 3, c = u & 7;
        va2[i] = *reinterpret_cast<const uint4*>(A + (rowBase + r) * 1024 + (kt + 1) * 64 + c * 8);
        vw2[i] = *reinterpret_cast<const uint4*>(W + (colBase + r) * 1024 + (kt + 1) * 64 + c * 8);
      }
    }
    const char* ach = reinterpret_cast<const char*>(As[cur]);
    const char* bch = reinterpret_cast<const char*>(Bs[cur]);
#pragma unroll
    for (int kk = 0; kk < 2; kk++){
      bf16x8 af[4], bfr[4];
#pragma unroll
      for (int mi = 0; mi < 4; mi++){
        int row = wm + mi * 16 + (lane & 15);
        int ob = (row * 128 + kk * 64 + (lane >> 4) * 16) ^ ((row & 7) << 4);
        af[mi] = ld_frag_lds(ach, ob);
      }
#pragma unroll
      for (int ni = 0; ni < 4; ni++){
        int row = wn + ni * 16 + (lane & 15);
        int ob = (row * 128 + kk * 64 + (lane >> 4) * 16) ^ ((row & 7) << 4);
        bfr[ni] = ld_frag_lds(bch, ob);
      }
#pragma unroll
      for (int mi = 0; mi < 4; mi++)
#pragma unroll
        for (int ni = 0; ni < 4; ni++)
          acc[mi][ni] = __builtin_amdgcn_mfma_f32_16x16x32_bf16(af[mi], bfr[ni], acc[mi][ni], 0, 0, 0);
    }
    if (kt < 15){
#pragma unroll
      for (int i = 0; i < 4; i++){
        int u = tid + i * 256;
        int r = u >> 3, c = u & 7;
        int ob = (r * 128 + c * 16) ^ ((r & 7) << 4);
        *reinterpret_cast<uint4*>(reinterpret_cast<char*>(As[cur ^ 1]) + ob) = va2[i];
        *reinterpret_cast<uint4*>(reinterpret_cast<char*>(Bs[cur ^ 1]) + ob) = vw2[i];
      }
      __syncthreads();
    }
    cur ^= 1;
  }

#pragma unroll
  for (int mi = 0; mi < 4; mi++){
#pragma unroll
    for (int ni = 0; ni < 4; ni++){
      long gn = colBase + wn + ni * 16 + (lane & 15);
      long h = gn >> 6, hd = gn & 63;
      if (mode == MODE_Q){
        float bb = bq[gn];
#pragma unroll
        for (int r = 0; r < 4; r++){
          long gm = rowBase + wm + mi * 16 + ((lane >> 4) << 2) + r;
          long b = gm >> 9, s = gm & 511;
          qbuf[((b * SH + h) * SS + s) * SHD + hd] =
              f2bf((acc[mi][ni][r] + bb) * QSCALE);
        }
      } else if (mode == MODE_K){
#pragma unroll
        for (int r = 0; r < 4; r++){
          long gm = rowBase + wm + mi * 16 + ((lane >> 4) << 2) + r;
          long b = gm >> 12, kv = gm & 4095;
          long idx = ((b * SH + h) * SKV + kv) * SHD + hd;
          float val = acc[mi][ni][r];
          outK[idx] = val;
          kbuf[idx] = f2bf(val);
        }
      } else { // MODE_V: f32 updated_v + fused bf16 transpose
        float bb = bv[gn];
        long gmBase = rowBase + wm + mi * 16 + ((lane >> 4) << 2);
        long b = gmBase >> 12, kv = gmBase & 4095;
        long fidx = ((b * SH + h) * SKV + kv) * SHD + hd;
        ushort4 pk;
        float v0 = acc[mi][ni][0] + bb; outV[fidx          ] = v0; pk.x = f2bf(v0);
        float v1 = acc[mi][ni][1] + bb; outV[fidx +     SHD] = v1; pk.y = f2bf(v1);
        float v2 = acc[mi][ni][2] + bb; outV[fidx + 2 * SHD] = v2; pk.z = f2bf(v2);
        float v3 = acc[mi][ni][3] + bb; outV[fidx + 3 * SHD] = v3; pk.w = f2bf(v3);
        *reinterpret_cast<ushort4*>(vTbuf + ((b * SH + h) * SHD + hd) * SKV + kv) = pk;
      }
    }
  }
}

// ---------- OUT projection: R12-verified 128^2 dbuf ----------
__global__ __launch_bounds__(256) void gemm_out(const u16* __restrict__ A,
                                                const u16* __restrict__ W,
                                                const float* __restrict__ bias,
                                                float* __restrict__ outF)
{
  __shared__ u16 As[2][128*64];
  __shared__ u16 Bs[2][128*64];
  const int tid  = threadIdx.x;
  const int lane = tid & 63;
  const int wm   = ((tid >> 6) >> 1) * 64;
  const int wn   = ((tid >> 6) & 1) * 64;
  const long rowBase = (long)blockIdx.x * 128;
  const long colBase = (long)blockIdx.y * 128;

  f32x4 acc[4][4];
#pragma unroll
  for (int i = 0; i < 4; i++)
#pragma unroll
    for (int j = 0; j < 4; j++)
      acc[i][j] = (f32x4){0.f, 0.f, 0.f, 0.f};

  uint4 va[4], vw[4];
#pragma unroll
  for (int i = 0; i < 4; i++){
    int u = tid + i * 256;
    int r = u >> 3, c = u & 7;
    va[i] = *reinterpret_cast<const uint4*>(A + (rowBase + r) * 1024 + c * 8);
    vw[i] = *reinterpret_cast<const uint4*>(W + (colBase + r) * 1024 + c * 8);
  }
#pragma unroll
  for (int i = 0; i < 4; i++){
    int u = tid + i * 256;
    int r = u >> 3, c = u & 7;
    int ob = (r * 128 + c * 16) ^ ((r & 7) << 4);
    *reinterpret_cast<uint4*>(reinterpret_cast<char*>(As[0]) + ob) = va[i];
    *reinterpret_cast<uint4*>(reinterpret_cast<char*>(Bs[0]) + ob) = vw[i];
  }
  __syncthreads();

  int cur = 0;
  for (int kt = 0; kt < 16; ++kt){
    uint4 va2[4], vw2[4];
    if (kt < 15){
#pragma unroll
      for (int i = 0; i < 4; i++){
        int u = tid + i * 256;
        int r = u >> 3, c = u & 7;
        va2[i] = *reinterpret_cast<const uint4*>(A + (rowBase + r) * 1024 + (kt + 1) * 64 + c * 8);
        vw2[i] = *reinterpret_cast<const uint4*>(W + (colBase + r) * 1024 + (kt + 1) * 64 + c * 8);
      }
    }
    const char* ach = reinterpret_cast<const char*>(As[cur]);
    const char* bch = reinterpret_cast<const char*>(Bs[cur]);
#pragma unroll
    for (int kk = 0; kk < 2; kk++){
      bf16x8 af[4], bfr[4];
#pragma unroll
      for (int mi = 0; mi < 4; mi++){
        int row = wm + mi * 16 + (lane & 15);
        int ob = (row * 128 + kk * 64 + (lane >> 4) * 16) ^ ((row & 7) << 4);
        af[mi] = ld_frag_lds(ach, ob);
      }
#pragma unroll
      for (int ni = 0; ni < 4; ni++){
        int row = wn + ni * 16 + (lane & 15);
        int ob = (row * 128 + kk * 64 + (lane >> 4) * 16) ^ ((row & 7) << 4);
        bfr[ni] = ld_frag_lds(bch, ob);
      }
#pragma unroll
      for (int mi = 0; mi < 4; mi++)
#pragma unroll
        for (int ni = 0; ni < 4; ni++)
          acc[mi][ni] = __builtin_amdgcn_mfma_f32_16x16x32_bf16(af[mi], bfr[ni], acc[mi][ni], 0, 0, 0);
    }
    if (kt < 15){
#pragma unroll
      for (int i = 0; i < 4; i++){
        int u = tid + i * 256;
        int r = u >> 3, c = u & 7;
        int ob = (r * 128 + c * 16) ^ ((r & 7) << 4);
        *reinterpret_cast<uint4*>(reinterpret_cast<char*>(As[cur ^ 1]) + ob) = va2[i];
        *reinterpret_cast<uint4*>(reinterpret_cast<char*>(Bs[cur ^ 1]) + ob) = vw2[i];
      }
      __syncthreads();
    }
    cur ^= 1;
  }

#pragma unroll
  for (int mi = 0; mi < 4; mi++){
#pragma unroll
    for (int ni = 0; ni < 4; ni++){
      long gn = colBase + wn + ni * 16 + (lane & 15);
      float bb = bias[gn];
#pragma unroll
      for (int r = 0; r < 4; r++){
        long gm = rowBase + wm + mi * 16 + ((lane >> 4) << 2) + r;
        outF[gm * 1024 + gn] = acc[mi][ni][r] + bb;
      }
    }
  }
}

// ---------- flash attention partial (R12-verified, unchanged) ----------
__global__ __launch_bounds__(512) void attn_partial(const u16* __restrict__ qb,
                                                    const u16* __restrict__ kb,
                                                    const u16* __restrict__ vTb,
                                                    u16* __restrict__ opartB,
                                                    float* __restrict__ ml){
  __shared__ u16 Klds[2][64 * 64];
  __shared__ u16 Vlds[2][64 * 64];
  __shared__ u16 PT[8][16 * 72];
  const int tid  = threadIdx.x;
  const int lane = tid & 63;
  const int wid  = tid >> 6;
  const int c    = lane & 15;
  const int hi   = lane >> 4;
  const long bh  = blockIdx.x;
  const int  qt  = blockIdx.y;
  const int  split = blockIdx.z;

  const u16* qp = qb + (bh * SS + qt * 128 + wid * 16 + c) * SHD + hi * 8;
  const bf16x8 bq0 = ld_frag_g(qp);
  const bf16x8 bq1 = ld_frag_g(qp + 32);

  f32x4 acc[4];
#pragma unroll
  for (int i = 0; i < 4; i++) acc[i] = (f32x4){0.f, 0.f, 0.f, 0.f};
  float mrun = -INFINITY;
  f32x4 lrunv = (f32x4){0.f, 0.f, 0.f, 0.f};

  const u16* kbase = kb  + bh * SKV * SHD;
  const u16* vbase = vTb + bh * SHD * SKV;
  u16* pt = &PT[wid][0];
  const int sr  = tid >> 3;
  const int scc = tid & 7;
  const int sob = (sr * 128 + scc * 16) ^ ((sr & 7) << 4);
  const int t0 = split * 16;

  {
    uint4 kv4 = *reinterpret_cast<const uint4*>(kbase + (t0 * 64 + sr) * SHD + scc * 8);
    uint4 vv4 = *reinterpret_cast<const uint4*>(vbase + (long)sr * SKV + t0 * 64 + scc * 8);
    *reinterpret_cast<uint4*>(reinterpret_cast<char*>(Klds[0]) + sob) = kv4;
    *reinterpret_cast<uint4*>(reinterpret_cast<char*>(Vlds[0]) + sob) = vv4;
  }
  __syncthreads();

  int cur = 0;
  for (int kt = t0; kt < t0 + 16; ++kt){
    const bool hn = kt + 1 < t0 + 16;
    uint4 kn, vn;
    if (hn){
      kn = *reinterpret_cast<const uint4*>(kbase + ((kt + 1) * 64 + sr) * SHD + scc * 8);
      vn = *reinterpret_cast<const uint4*>(vbase + (long)sr * SKV + (kt + 1) * 64 + scc * 8);
    }
    const char* kch = reinterpret_cast<const char*>(Klds[cur]);
    const char* vch = reinterpret_cast<const char*>(Vlds[cur]);

    f32x4 sT[4];
#pragma unroll
    for (int ni = 0; ni < 4; ni++){
      int krow = ni * 16 + c;
      int swz = (krow & 7) << 4;
      int a0 = (krow * 128 + hi * 16) ^ swz;
      int a1 = (krow * 128 + 64 + hi * 16) ^ swz;
      f32x4 z = (f32x4){0.f, 0.f, 0.f, 0.f};
      sT[ni] = __builtin_amdgcn_mfma_f32_16x16x32_bf16(ld_frag_lds(kch, a0), bq0, z, 0, 0, 0);
      sT[ni] = __builtin_amdgcn_mfma_f32_16x16x32_bf16(ld_frag_lds(kch, a1), bq1, sT[ni], 0, 0, 0);
    }
    f32x4 mv = __builtin_elementwise_max(__builtin_elementwise_max(sT[0], sT[1]),
                                         __builtin_elementwise_max(sT[2], sT[3]));
    float t = fmaxf(fmaxf(mv[0], mv[1]), fmaxf(mv[2], mv[3]));
    if (!__all(t <= mrun + DEFER_THR)){
      float tr = fmaxf(t, __shfl_xor(t, 16));
      tr = fmaxf(tr, __shfl_xor(tr, 32));
      float mn = fmaxf(mrun, tr);
      float al = exp2f(mrun - mn);
      lrunv *= al;
#pragma unroll
      for (int ni = 0; ni < 4; ni++) acc[ni] *= al;
      mrun = mn;
    }
#pragma unroll
    for (int ni = 0; ni < 4; ni++){
      f32x4 p;
      p[0] = exp2f(sT[ni][0] - mrun); p[1] = exp2f(sT[ni][1] - mrun);
      p[2] = exp2f(sT[ni][2] - mrun); p[3] = exp2f(sT[ni][3] - mrun);
      lrunv += p;
      unsigned lo = pack_bf_trunc(p[0], p[1]);
      unsigned hp = pack_bf_trunc(p[2], p[3]);
      uint2 w; w.x = lo; w.y = hp;
      *reinterpret_cast<uint2*>(pt + c * 72 + ni * 16 + hi * 4) = w;
    }
#pragma unroll
    for (int m = 0; m < 2; m++){
      bf16x8 pfrag = __builtin_bit_cast(bf16x8,
          *reinterpret_cast<const uint4*>(pt + c * 72 + m * 32 + hi * 8));
#pragma unroll
      for (int ni = 0; ni < 4; ni++){
        int vrow = ni * 16 + c;
        int av = (vrow * 128 + m * 64 + hi * 16) ^ ((vrow & 7) << 4);
        acc[ni] = __builtin_amdgcn_mfma_f32_16x16x32_bf16(ld_frag_lds(vch, av), pfrag, acc[ni], 0, 0, 0);
      }
    }
    if (hn){
      *reinterpret_cast<uint4*>(reinterpret_cast<char*>(Klds[cur ^ 1]) + sob) = kn;
      *reinterpret_cast<uint4*>(reinterpret_cast<char*>(Vlds[cur ^ 1]) + sob) = vn;
      __syncthreads();
    }
    cur ^= 1;
  }

  float l = (lrunv[0] + lrunv[1]) + (lrunv[2] + lrunv[3]);
  l += __shfl_xor(l, 16);
  l += __shfl_xor(l, 32);
  const long row = bh * SS + (long)qt * 128 + wid * 16 + c;
  u16* ob = opartB + ((long)split * NROWS + row) * SHD;
#pragma unroll
  for (int ni = 0; ni < 4; ni++){
    ushort4 pk;
    pk.x = f2bf(acc[ni][0]); pk.y = f2bf(acc[ni][1]);
    pk.z = f2bf(acc[ni][2]); pk.w = f2bf(acc[ni][3]);
    *reinterpret_cast<ushort4*>(ob + ni * 16 + hi * 4) = pk;
  }
  if (hi == 0){
    ml[(long)split * NROWS + row] = mrun;
    ml[(long)NSPLIT * NROWS + (long)split * NROWS + row] = l;
  }
}

// ---------- combine bf16 partials -> attnb bf16 [B,S,D] (base-2 weights) ----------
__global__ __launch_bounds__(256) void attn_combine(const u16* __restrict__ opartB,
                                                    const float* __restrict__ ml,
                                                    u16* __restrict__ attnb){
  long idx4 = (long)blockIdx.x * 256 + threadIdx.x;
  long row = idx4 >> 4;
  int  c   = (int)(idx4 & 15);
  float m0 = ml[row], m1 = ml[NROWS + row], m2 = ml[2L*NROWS + row], m3 = ml[3L*NROWS + row];
  float M = fmaxf(fmaxf(m0, m1), fmaxf(m2, m3));
  float w0 = exp2f(m0 - M), w1 = exp2f(m1 - M), w2 = exp2f(m2 - M), w3 = exp2f(m3 - M);
  const float* lb = ml + (long)NSPLIT * NROWS;
  float L = w0*lb[row] + w1*lb[NROWS+row] + w2*lb[2L*NROWS+row] + w3*lb[3L*NROWS+row];
  float inv = 1.f / L;
  const ushort4* op = reinterpret_cast<const ushort4*>(opartB);
  ushort4 v0 = op[(0L*NROWS + row) * 16 + c];
  ushort4 v1 = op[(1L*NROWS + row) * 16 + c];
  ushort4 v2 = op[(2L*NROWS + row) * 16 + c];
  ushort4 v3 = op[(3L*NROWS + row) * 16 + c];
  float4 val;
  val.x = (w0*bf2f(v0.x) + w1*bf2f(v1.x) + w2*bf2f(v2.x) + w3*bf2f(v3.x)) * inv;
  val.y = (w0*bf2f(v0.y) + w1*bf2f(v1.y) + w2*bf2f(v2.y) + w3*bf2f(v3.y)) * inv;
  val.z = (w0*bf2f(v0.z) + w1*bf2f(v1.z) + w2*bf2f(v2.z) + w3*bf2f(v3.z)) * inv;
  val.w = (w0*bf2f(v0.w) + w1*bf2f(v1.w) + w2*bf2f(v2.w) + w3*bf2f(v3.w)) * inv;
  long bh = row >> 9, s = row & 511;
  long b = bh >> 4, h = bh & 15;
  ushort4 u;
  u.x = f2bf(val.x); u.y = f2bf(val.y); u.z = f2bf(val.z); u.w = f2bf(val.w);
  reinterpret_cast<ushort4*>(attnb)[((b * SS + s) * SD + h * SHD) / 4 + c] = u;
}

extern "C" void kernel_launch(void* const* d_in, const int* in_sizes, int n_in,
                              void* d_out, int out_size, void* d_ws, size_t ws_size,
                              hipStream_t stream)
{
  const float* x  = (const float*)d_in[0];
  const float* xa = (const float*)d_in[1];
  const float* Wq = (const float*)d_in[2];
  const float* bq = (const float*)d_in[3];
  const float* Wk = (const float*)d_in[4];
  const float* Wv = (const float*)d_in[5];
  const float* bv = (const float*)d_in[6];
  const float* Wo = (const float*)d_in[7];
  const float* bo = (const float*)d_in[8];

  float* outO = (float*)d_out;
  float* outK = outO + (long)SB * SS * SD;
  float* outV = outK + (long)SB * SH * SKV * SHD;

  u16* ws   = (u16*)d_ws;
  u16* xb   = ws;                                     // 2M u16 (reused as attnb)
  u16* xab  = xb   + 2097152L;                        // 16.7M u16 (reused as opartB)
  u16* Wqb  = xab  + 16777216L;                       // 4x 1M u16 (Wq,Wk,Wv,Wo)
  u16* Wkb  = Wqb  + 1048576L;
  u16* Wvb  = Wkb  + 1048576L;
  u16* Wob  = Wvb  + 1048576L;
  u16* qbuf = Wob  + 1048576L;                        // [B,H,S,HD] bf16
  u16* kbuf = qbuf + 2097152L;                        // [B,H,KV,HD] bf16
  u16* vTbuf= kbuf + 16777216L;                       // [B,H,HD,KV] bf16
  u16* mlb  = vTbuf+ 16777216L;                       // 8*32768 f32

  u16*   attnb  = xb;                                 // alias: xb dead after proj_all
  u16*   opartB = xab;                                // alias: xab dead after proj_all
  float* ml     = (float*)mlb;

  cast_all<<<22528, 256, 0, stream>>>(x, xa, Wq, Wk, Wv, Wo, xb, xab, Wqb);

  proj_all<<<2176, 256, 0, stream>>>(xb, xab, Wqb, Wkb, Wvb, bq, bv,
                                     qbuf, outK, kbuf, outV, vTbuf);
  attn_partial<<<dim3(64, 4, NSPLIT), 512, 0, stream>>>(qbuf, kbuf, vTbuf, opartB, ml);
  attn_combine<<<2048, 256, 0, stream>>>(opartB, ml, attnb);
  gemm_out    <<<dim3(16, 8), 256, 0, stream>>>(attnb, Wob, bo, outO);
}